// Round 2
// baseline (6182.700 us; speedup 1.0000x reference)
//
#include <hip/hip_runtime.h>
#include <math.h>

#define NSEQ 2048
#define NTOK 49
#define DIMD 512
#define HEADS 8
#define DH 32
#define DI 256    // HEADS*DH
#define QKV3 768  // 3*DI

// ws float layout: [0,1568) cos, [1568,3136) sin, [4096, 4096+NSEQ*NTOK*DI) attnout
#define WS_COS 0
#define WS_SIN 1568
#define WS_ATT 4096

__global__ __launch_bounds__(256) void k_rope(const float* __restrict__ re, float* __restrict__ ws) {
    int i = blockIdx.x * 256 + threadIdx.x;
    if (i < NTOK * DH) {
        float v = re[i];
        ws[WS_COS + i] = cosf(v);
        ws[WS_SIN + i] = sinf(v);
    }
}

// one wave per token: L2-norm over 512, write xn = x/max(||x||,eps)*gamma*sqrt(512)
__global__ __launch_bounds__(256) void k_norm(const float* __restrict__ x,
                                              const float* __restrict__ gamma,
                                              float* __restrict__ xn) {
    int token = blockIdx.x * 4 + (threadIdx.x >> 6);
    int lane  = threadIdx.x & 63;
    const float4* xin = (const float4*)(x + (size_t)token * DIMD);
    float4 a = xin[lane * 2], b = xin[lane * 2 + 1];
    float ss = a.x*a.x + a.y*a.y + a.z*a.z + a.w*a.w
             + b.x*b.x + b.y*b.y + b.z*b.z + b.w*b.w;
    #pragma unroll
    for (int off = 32; off; off >>= 1) ss += __shfl_xor(ss, off);
    float nrm = fmaxf(sqrtf(ss), 1e-12f);
    float s = 22.62741699796952f / nrm;  // sqrt(512)/norm
    const float4* gp = (const float4*)gamma;
    float4 g0 = gp[lane * 2], g1 = gp[lane * 2 + 1];
    float4 o0, o1;
    o0.x = a.x*s*g0.x; o0.y = a.y*s*g0.y; o0.z = a.z*s*g0.z; o0.w = a.w*s*g0.w;
    o1.x = b.x*s*g1.x; o1.y = b.y*s*g1.y; o1.z = b.z*s*g1.z; o1.w = b.w*s*g1.w;
    float4* op = (float4*)(xn + (size_t)token * DIMD);
    op[lane * 2] = o0; op[lane * 2 + 1] = o1;
}

// fused per-(seq,head): qkv GEMM + gate + rotary + softmax + PV
__global__ __launch_bounds__(256) void k_attn(const float* __restrict__ xn,
                                              const float* __restrict__ wqkv,
                                              const float* __restrict__ wg,
                                              const float* __restrict__ bg,
                                              const float* __restrict__ ws,
                                              float* __restrict__ attnout) {
    // XCD swizzle: all 8 heads of a seq share bid%8 (same XCD) for xn L2 reuse
    int r = blockIdx.x & 7, j = blockIdx.x >> 3;
    int seq  = (j >> 3) * 8 + r;
    int head = j & 7;

    __shared__ float s_xn[NTOK][68];                      // 64-wide K chunk (+pad)
    __shared__ float s_q[NTOK][33], s_k[NTOK][33], s_v[NTOK][33];
    __shared__ float s_sc[NTOK][52];
    __shared__ float s_g[NTOK];

    int t  = threadIdx.x;
    int c  = t & 31;    // column within head (0..31)
    int tg = t >> 5;    // token group (0..7)

    int irow[7];
    bool ival[7];
    #pragma unroll
    for (int rr = 0; rr < 7; ++rr) {
        int i = tg + 8 * rr;
        ival[rr] = (i < NTOK);
        irow[rr] = ival[rr] ? i : (NTOK - 1);
    }

    float accq[7], acck[7], accv[7], accg[7];
    #pragma unroll
    for (int rr = 0; rr < 7; ++rr) { accq[rr] = acck[rr] = accv[rr] = accg[rr] = 0.f; }

    const float* xb = xn + (size_t)seq * NTOK * DIMD;

    for (int kc = 0; kc < DIMD; kc += 64) {
        __syncthreads();
        for (int id = t; id < NTOK * 16; id += 256) {
            int i = id >> 4, k4 = id & 15;
            float4 v4 = *(const float4*)(xb + (size_t)i * DIMD + kc + k4 * 4);
            *(float4*)&s_xn[i][k4 * 4] = v4;
        }
        __syncthreads();
        #pragma unroll 4
        for (int kk = 0; kk < 16; ++kk) {
            int k = kc + kk * 4;
            float wqv[4], wkv[4], wvv[4], wgv[4];
            #pragma unroll
            for (int u = 0; u < 4; ++u) {
                size_t rowo = (size_t)(k + u) * QKV3 + head * DH + c;
                wqv[u] = wqkv[rowo];
                wkv[u] = wqkv[rowo + DI];
                wvv[u] = wqkv[rowo + 2 * DI];
            }
            if (c == 0) {
                #pragma unroll
                for (int u = 0; u < 4; ++u) wgv[u] = wg[(k + u) * HEADS + head];
            }
            #pragma unroll
            for (int rr = 0; rr < 7; ++rr) {
                float4 xv = *(const float4*)&s_xn[irow[rr]][kk * 4];
                accq[rr] += xv.x*wqv[0] + xv.y*wqv[1] + xv.z*wqv[2] + xv.w*wqv[3];
                acck[rr] += xv.x*wkv[0] + xv.y*wkv[1] + xv.z*wkv[2] + xv.w*wkv[3];
                accv[rr] += xv.x*wvv[0] + xv.y*wvv[1] + xv.z*wvv[2] + xv.w*wvv[3];
                if (c == 0)
                    accg[rr] += xv.x*wgv[0] + xv.y*wgv[1] + xv.z*wgv[2] + xv.w*wgv[3];
            }
        }
    }

    #pragma unroll
    for (int rr = 0; rr < 7; ++rr) {
        if (ival[rr]) {
            int i = irow[rr];
            s_q[i][c] = accq[rr];
            s_k[i][c] = acck[rr];
            s_v[i][c] = accv[rr];
        }
    }
    if (c == 0) {
        float bgv = bg[head];
        #pragma unroll
        for (int rr = 0; rr < 7; ++rr) {
            if (ival[rr]) {
                float z = accg[rr] + bgv;
                s_g[irow[rr]] = 1.f / (1.f + expf(-z));
            }
        }
    }
    __syncthreads();

    // rotary on q,k (in LDS): out[2p] = x[2p]*cos[2p] - x[2p+1]*sin[2p]
    //                         out[2p+1] = x[2p+1]*cos[2p+1] + x[2p]*sin[2p+1]
    const float* cost = ws + WS_COS;
    const float* sint = ws + WS_SIN;
    for (int id = t; id < NTOK * 16; id += 256) {
        int i = id >> 4, p = id & 15;
        float c0 = cost[i * DH + 2 * p],     s0 = sint[i * DH + 2 * p];
        float c1 = cost[i * DH + 2 * p + 1], s1 = sint[i * DH + 2 * p + 1];
        float q0 = s_q[i][2 * p], q1 = s_q[i][2 * p + 1];
        s_q[i][2 * p]     = q0 * c0 - q1 * s0;
        s_q[i][2 * p + 1] = q1 * c1 + q0 * s1;
        float k0 = s_k[i][2 * p], k1 = s_k[i][2 * p + 1];
        s_k[i][2 * p]     = k0 * c0 - k1 * s0;
        s_k[i][2 * p + 1] = k1 * c1 + k0 * s1;
    }
    __syncthreads();

    // scores = q k^T * 1/sqrt(32)
    for (int id = t; id < NTOK * NTOK; id += 256) {
        int i = id / NTOK, jj = id - i * NTOK;
        float acc = 0.f;
        #pragma unroll
        for (int u = 0; u < 8; ++u) {
            float4 qv = *(const float4*)&s_q[i][u * 4];
            float4 kv = *(const float4*)&s_k[jj][u * 4];
            acc += qv.x*kv.x + qv.y*kv.y + qv.z*kv.z + qv.w*kv.w;
        }
        s_sc[i][jj] = acc * 0.17677669529663687f;
    }
    __syncthreads();

    // softmax rows: one wave per row
    int wave = t >> 6, lane = t & 63;
    for (int i = wave; i < NTOK; i += 4) {
        float v = (lane < NTOK) ? s_sc[i][lane] : -3.4e38f;
        float m = v;
        #pragma unroll
        for (int off = 32; off; off >>= 1) m = fmaxf(m, __shfl_xor(m, off));
        float e = (lane < NTOK) ? expf(v - m) : 0.f;
        float ssum = e;
        #pragma unroll
        for (int off = 32; off; off >>= 1) ssum += __shfl_xor(ssum, off);
        if (lane < NTOK) s_sc[i][lane] = e / ssum;
    }
    __syncthreads();

    // PV + gate, write to ws attnout (seq, token, head*32+d)
    float* ob = attnout + (size_t)seq * NTOK * DI + head * DH;
    for (int id = t; id < NTOK * DH; id += 256) {
        int i = id >> 5, d = id & 31;
        float acc = 0.f;
        #pragma unroll 7
        for (int jj = 0; jj < NTOK; ++jj) acc += s_sc[i][jj] * s_v[jj][d];
        ob[(size_t)i * DI + d] = acc * s_g[i];
    }
}

// out = attnout(100352x256) @ w_out(256x512), 64x64 tiles
__global__ __launch_bounds__(256) void k_out(const float* __restrict__ att,
                                             const float* __restrict__ wout,
                                             float* __restrict__ out) {
    __shared__ float sA[64][33];
    __shared__ float sB[32][68];
    int t = threadIdx.x;
    int m0 = blockIdx.x * 64;
    int n0 = blockIdx.y * 64;
    int tx = t & 15, ty = t >> 4;
    float acc[4][4];
    #pragma unroll
    for (int a = 0; a < 4; ++a)
        #pragma unroll
        for (int b = 0; b < 4; ++b) acc[a][b] = 0.f;

    for (int kc = 0; kc < 256; kc += 32) {
        __syncthreads();
        for (int id = t; id < 512; id += 256) {
            int m = id >> 3, k4 = id & 7;
            float4 v4 = *(const float4*)(att + (size_t)(m0 + m) * DI + kc + k4 * 4);
            *(float4*)&sA[m][k4 * 4] = v4;
        }
        for (int id = t; id < 512; id += 256) {
            int k = id >> 4, n4 = id & 15;
            float4 v4 = *(const float4*)(wout + (size_t)(kc + k) * DIMD + n0 + n4 * 4);
            *(float4*)&sB[k][n4 * 4] = v4;
        }
        __syncthreads();
        #pragma unroll 8
        for (int k = 0; k < 32; ++k) {
            float a0 = sA[ty * 4 + 0][k], a1 = sA[ty * 4 + 1][k];
            float a2 = sA[ty * 4 + 2][k], a3 = sA[ty * 4 + 3][k];
            float4 bv = *(const float4*)&sB[k][tx * 4];
            acc[0][0] += a0 * bv.x; acc[0][1] += a0 * bv.y; acc[0][2] += a0 * bv.z; acc[0][3] += a0 * bv.w;
            acc[1][0] += a1 * bv.x; acc[1][1] += a1 * bv.y; acc[1][2] += a1 * bv.z; acc[1][3] += a1 * bv.w;
            acc[2][0] += a2 * bv.x; acc[2][1] += a2 * bv.y; acc[2][2] += a2 * bv.z; acc[2][3] += a2 * bv.w;
            acc[3][0] += a3 * bv.x; acc[3][1] += a3 * bv.y; acc[3][2] += a3 * bv.z; acc[3][3] += a3 * bv.w;
        }
    }
    #pragma unroll
    for (int mm = 0; mm < 4; ++mm) {
        float4 o;
        o.x = acc[mm][0]; o.y = acc[mm][1]; o.z = acc[mm][2]; o.w = acc[mm][3];
        *(float4*)(out + (size_t)(m0 + ty * 4 + mm) * DIMD + n0 + tx * 4) = o;
    }
}

extern "C" void kernel_launch(void* const* d_in, const int* in_sizes, int n_in,
                              void* d_out, int out_size, void* d_ws, size_t ws_size,
                              hipStream_t stream) {
    const float* x     = (const float*)d_in[0];
    const float* rote  = (const float*)d_in[1];
    const float* gamma = (const float*)d_in[2];
    const float* wqkv  = (const float*)d_in[3];
    const float* wg    = (const float*)d_in[4];
    const float* bg    = (const float*)d_in[5];
    const float* wout  = (const float*)d_in[6];
    float* out = (float*)d_out;
    float* ws  = (float*)d_ws;
    float* xnp = out;            // reuse d_out as xn scratch (overwritten by k_out)
    float* att = ws + WS_ATT;    // 100352*256 floats = 102.8 MB

    k_rope<<<7, 256, 0, stream>>>(rote, ws);
    k_norm<<<25088, 256, 0, stream>>>(x, gamma, xnp);
    k_attn<<<16384, 256, 0, stream>>>(xnp, wqkv, wg, bg, ws, att);
    k_out<<<dim3(1568, 8), 256, 0, stream>>>(att, wout, out);
}

// Round 6
// 1020.537 us; speedup vs baseline: 6.0583x; 6.0583x over previous
//
#include <hip/hip_runtime.h>
#include <hip/hip_bf16.h>
#include <math.h>

#define NSEQ 2048
#define NTOK 49
#define DIMD 512
#define HEADS 8
#define DH 32
#define DI 256
#define QKV3 768

typedef __bf16 bf16x8 __attribute__((ext_vector_type(8)));
typedef float f32x4 __attribute__((ext_vector_type(4)));

// ws float-offsets
#define WS_COS 0
#define WS_SIN 1568
#define WS_WPK 4096            // 49*16*64*8 = 401408 bf16 = 200704 floats
#define WS_WOPK 204800         // 32*8*64*8 = 131072 bf16 = 65536 floats
#define WS_ATT 270336          // att bf16: 100352*256 = 25690112 bf16

// LDS byte offsets (k_attn)
#define OFF_X 0                // 49 rows * 1024 B (bf16[512], XOR-swizzled 16B chunks)
#define OFF_Q 50176            // [8][49][40] bf16, row stride 80 B
#define OFF_K 81536            // [8][49][40]
#define OFF_VT 112896          // [8][32][72] bf16, row stride 144 B (token-major transposed V)
#define OFF_P 0                // [64][72] bf16, stride 144 (union with s_x, dead by then)
#define OFF_G 9216             // [8][64] f32 (union with s_x)
#define LDS_BYTES 149760

__device__ __forceinline__ unsigned short f2bf(float x) {
    union { float f; unsigned u; } c; c.f = x;
    unsigned r = c.u + 0x7FFFu + ((c.u >> 16) & 1u);
    return (unsigned short)(r >> 16);
}

__global__ __launch_bounds__(256) void k_rope(const float* __restrict__ re, float* __restrict__ ws) {
    int i = blockIdx.x * 256 + threadIdx.x;
    if (i < NTOK * DH) {
        float v = re[i];
        ws[WS_COS + i] = cosf(v);
        ws[WS_SIN + i] = sinf(v);
    }
}

// Pack W = [wqkv | wg] (512 x 776, zero-pad to 784) into B-fragment order:
// wpk[((nt*16+ks)*64 + lane)*8 + j] = W[k][n], n = nt*16+(lane&15), k = ks*32+(lane>>4)*8+j
__global__ __launch_bounds__(256) void k_pack(const float* __restrict__ wqkv,
                                              const float* __restrict__ wg,
                                              unsigned short* __restrict__ wpk) {
    int idx = blockIdx.x * 256 + threadIdx.x;   // 49*16*64*8 = 401408 exact
    int j = idx & 7;
    int lane = (idx >> 3) & 63;
    int ks = (idx >> 9) & 15;
    int nt = idx >> 13;
    int n = nt * 16 + (lane & 15);
    int k = ks * 32 + (lane >> 4) * 8 + j;
    float v = 0.f;
    if (n < 768) v = wqkv[k * QKV3 + n];
    else if (n < 776) v = wg[k * HEADS + (n - 768)];
    wpk[idx] = f2bf(v);
}

// Pack w_out (256 x 512) the same way: nt 0..31, ks 0..7
__global__ __launch_bounds__(256) void k_pack_out(const float* __restrict__ wout,
                                                  unsigned short* __restrict__ wopk) {
    int idx = blockIdx.x * 256 + threadIdx.x;   // 32*8*64*8 = 131072 exact
    int j = idx & 7;
    int lane = (idx >> 3) & 63;
    int ks = (idx >> 9) & 7;
    int nt = idx >> 12;
    int n = nt * 16 + (lane & 15);
    int k = ks * 32 + (lane >> 4) * 8 + j;
    wopk[idx] = f2bf(wout[k * DIMD + n]);
}

// one wave per token: xn = x/max(||x||,eps)*gamma*sqrt(512), output bf16
__global__ __launch_bounds__(256) void k_norm(const float* __restrict__ x,
                                              const float* __restrict__ gamma,
                                              unsigned short* __restrict__ xn) {
    int token = blockIdx.x * 4 + (threadIdx.x >> 6);
    int lane  = threadIdx.x & 63;
    const float4* xin = (const float4*)(x + (size_t)token * DIMD);
    float4 a = xin[lane * 2], b = xin[lane * 2 + 1];
    float ss = a.x*a.x + a.y*a.y + a.z*a.z + a.w*a.w
             + b.x*b.x + b.y*b.y + b.z*b.z + b.w*b.w;
    #pragma unroll
    for (int off = 32; off; off >>= 1) ss += __shfl_xor(ss, off);
    float s = 22.62741699796952f / fmaxf(sqrtf(ss), 1e-12f);
    const float4* gp = (const float4*)gamma;
    float4 g0 = gp[lane * 2], g1 = gp[lane * 2 + 1];
    uint4 o;
    o.x = (unsigned)f2bf(a.x*s*g0.x) | ((unsigned)f2bf(a.y*s*g0.y) << 16);
    o.y = (unsigned)f2bf(a.z*s*g0.z) | ((unsigned)f2bf(a.w*s*g0.w) << 16);
    o.z = (unsigned)f2bf(b.x*s*g1.x) | ((unsigned)f2bf(b.y*s*g1.y) << 16);
    o.w = (unsigned)f2bf(b.z*s*g1.z) | ((unsigned)f2bf(b.w*s*g1.w) << 16);
    *(uint4*)(xn + (size_t)token * DIMD + lane * 8) = o;
}

__global__ __launch_bounds__(256, 1) void k_attn(const unsigned short* __restrict__ xn,
                                                 const float* __restrict__ ws,
                                                 const unsigned short* __restrict__ wpk,
                                                 const float* __restrict__ bg,
                                                 unsigned short* __restrict__ att) {
    __shared__ __align__(16) unsigned char L[LDS_BYTES];
    const int t = threadIdx.x;
    const int w = t >> 6, l = t & 63, lr = l & 15, lg = l >> 4;
    const int seq = blockIdx.x;

    // stage xn (bf16) into swizzled LDS: 49 rows x 1024 B
    const unsigned short* xb = xn + (size_t)seq * NTOK * DIMD;
    for (int id = t; id < NTOK * 64; id += 256) {
        int tok = id >> 6, ch = id & 63;
        uint4 v = *(const uint4*)(xb + tok * DIMD + ch * 8);
        *(uint4*)(L + OFF_X + tok * 1024 + ((ch * 16) ^ ((tok & 7) << 4))) = v;
    }

    // per-lane rope tables (this wave's q/k column dim is fixed: ddq)
    const float* cost = ws + WS_COS;
    const float* sint = ws + WS_SIN;
    const int ddq = ((w & 1) << 4) + lr;
    float ctab[16], stab[16];
    #pragma unroll
    for (int mt = 0; mt < 4; ++mt)
        #pragma unroll
        for (int r = 0; r < 4; ++r) {
            int tok = mt * 16 + lg * 4 + r; if (tok > 48) tok = 48;
            ctab[mt * 4 + r] = cost[tok * DH + ddq];
            stab[mt * 4 + r] = sint[tok * DH + ddq];
        }
    __syncthreads();

    // ---- phase 1: QKV+gate GEMM, N-tiles strided across waves ----
    float gacc[4][4];
    const bf16x8* wpf = (const bf16x8*)wpk;
    for (int nt = w; nt < 49; nt += 4) {
        f32x4 acc0 = {0.f,0.f,0.f,0.f}, acc1 = acc0, acc2 = acc0, acc3 = acc0;
        #pragma unroll 4
        for (int ks = 0; ks < 16; ++ks) {
            bf16x8 b = wpf[(nt * 16 + ks) * 64 + l];
            int kb = ks * 64 + lg * 16;
            int t0 = lr, t1 = 16 + lr, t2 = 32 + lr;
            bf16x8 a0 = *(const bf16x8*)(L + OFF_X + t0 * 1024 + (kb ^ ((t0 & 7) << 4)));
            bf16x8 a1 = *(const bf16x8*)(L + OFF_X + t1 * 1024 + (kb ^ ((t1 & 7) << 4)));
            bf16x8 a2 = *(const bf16x8*)(L + OFF_X + t2 * 1024 + (kb ^ ((t2 & 7) << 4)));
            bf16x8 a3 = *(const bf16x8*)(L + OFF_X + 48 * 1024 + kb);   // rows 49-63 clamped to 48
            acc0 = __builtin_amdgcn_mfma_f32_16x16x32_bf16(a0, b, acc0, 0, 0, 0);
            acc1 = __builtin_amdgcn_mfma_f32_16x16x32_bf16(a1, b, acc1, 0, 0, 0);
            acc2 = __builtin_amdgcn_mfma_f32_16x16x32_bf16(a2, b, acc2, 0, 0, 0);
            acc3 = __builtin_amdgcn_mfma_f32_16x16x32_bf16(a3, b, acc3, 0, 0, 0);
        }
        f32x4 acc[4] = {acc0, acc1, acc2, acc3};
        if (nt < 32) {
            // q or k tile: rotary in-register, store [tok][dd]
            bool isq = nt < 16;
            int h = (isq ? nt : nt - 16) >> 1;
            float sgn = (lr & 1) ? 1.f : -1.f;
            unsigned base = (isq ? OFF_Q : OFF_K) + (unsigned)(h * NTOK) * 80 + ddq * 2;
            #pragma unroll
            for (int mt = 0; mt < 4; ++mt)
                #pragma unroll
                for (int r = 0; r < 4; ++r) {
                    float v = acc[mt][r];
                    float p = __shfl_xor(v, 1);
                    float o = v * ctab[mt * 4 + r] + sgn * p * stab[mt * 4 + r];
                    int tok = mt * 16 + lg * 4 + r;
                    if (tok < NTOK) *(unsigned short*)(L + base + tok * 80) = f2bf(o);
                }
        } else if (nt < 48) {
            // v tile: store transposed [d][tok], 4 consecutive tokens per write
            int h = (nt - 32) >> 1;
            unsigned base = OFF_VT + (unsigned)(h * DH + ddq) * 144;
            #pragma unroll
            for (int mt = 0; mt < 4; ++mt) {
                int tok0 = mt * 16 + lg * 4;
                if (tok0 < NTOK) {
                    ushort4 pk;
                    pk.x = f2bf(acc[mt][0]); pk.y = f2bf(acc[mt][1]);
                    pk.z = f2bf(acc[mt][2]); pk.w = f2bf(acc[mt][3]);
                    *(ushort4*)(L + base + tok0 * 2) = pk;
                }
            }
        } else {
            #pragma unroll
            for (int mt = 0; mt < 4; ++mt)
                #pragma unroll
                for (int r = 0; r < 4; ++r) gacc[mt][r] = acc[mt][r];
        }
    }
    __syncthreads();

    // zero V^T pad tokens 49..71 (garbage from clamped tile writes), write gate
    for (int id = t; id < HEADS * DH * 23; id += 256) {
        int hd = id / 23, tk = 49 + id % 23;
        *(unsigned short*)(L + OFF_VT + hd * 144 + tk * 2) = 0;
    }
    if (w == 0 && lr < 8) {
        float bgv = bg[lr];
        #pragma unroll
        for (int mt = 0; mt < 4; ++mt)
            #pragma unroll
            for (int r = 0; r < 4; ++r) {
                int tok = mt * 16 + lg * 4 + r;
                if (tok < NTOK) {
                    float z = gacc[mt][r] + bgv;
                    *(float*)(L + OFF_G + (lr * 64 + tok) * 4) = 1.f / (1.f + __expf(-z));
                }
            }
    }
    __syncthreads();

    // ---- phase 2+3 per head: scores, softmax (in-register), PV, gated store ----
    const float scale = 0.17677669529663687f;
    for (int h = 0; h < HEADS; ++h) {
        int tq = 16 * w + lr; if (tq > 48) tq = 48;
        bf16x8 aq = *(const bf16x8*)(L + OFF_Q + (unsigned)(h * NTOK + tq) * 80 + lg * 16);
        int j0 = lr, j1 = 16 + lr, j2 = 32 + lr;
        bf16x8 b0 = *(const bf16x8*)(L + OFF_K + (unsigned)(h * NTOK + j0) * 80 + lg * 16);
        bf16x8 b1 = *(const bf16x8*)(L + OFF_K + (unsigned)(h * NTOK + j1) * 80 + lg * 16);
        bf16x8 b2 = *(const bf16x8*)(L + OFF_K + (unsigned)(h * NTOK + j2) * 80 + lg * 16);
        bf16x8 b3 = *(const bf16x8*)(L + OFF_K + (unsigned)(h * NTOK + 48) * 80 + lg * 16);
        f32x4 z = {0.f,0.f,0.f,0.f};
        f32x4 s0 = __builtin_amdgcn_mfma_f32_16x16x32_bf16(aq, b0, z, 0, 0, 0);
        f32x4 s1 = __builtin_amdgcn_mfma_f32_16x16x32_bf16(aq, b1, z, 0, 0, 0);
        f32x4 s2 = __builtin_amdgcn_mfma_f32_16x16x32_bf16(aq, b2, z, 0, 0, 0);
        f32x4 s3 = __builtin_amdgcn_mfma_f32_16x16x32_bf16(aq, b3, z, 0, 0, 0);
        f32x4 sv[4] = {s0, s1, s2, s3};
        float pw[4][4];
        #pragma unroll
        for (int r = 0; r < 4; ++r) {
            float m = -3.0e38f;
            #pragma unroll
            for (int nt2 = 0; nt2 < 4; ++nt2) {
                float v = sv[nt2][r] * scale;
                pw[nt2][r] = v;
                if (nt2 * 16 + lr < NTOK) m = fmaxf(m, v);
            }
            m = fmaxf(m, __shfl_xor(m, 1));
            m = fmaxf(m, __shfl_xor(m, 2));
            m = fmaxf(m, __shfl_xor(m, 4));
            m = fmaxf(m, __shfl_xor(m, 8));
            float sum = 0.f;
            #pragma unroll
            for (int nt2 = 0; nt2 < 4; ++nt2) {
                float e = (nt2 * 16 + lr < NTOK) ? __expf(pw[nt2][r] - m) : 0.f;
                pw[nt2][r] = e;
                sum += e;
            }
            sum += __shfl_xor(sum, 1);
            sum += __shfl_xor(sum, 2);
            sum += __shfl_xor(sum, 4);
            sum += __shfl_xor(sum, 8);
            float inv = 1.f / sum;
            #pragma unroll
            for (int nt2 = 0; nt2 < 4; ++nt2) pw[nt2][r] *= inv;
        }
        // P -> LDS (wave-local rows; no barrier needed)
        #pragma unroll
        for (int nt2 = 0; nt2 < 4; ++nt2)
            #pragma unroll
            for (int r = 0; r < 4; ++r) {
                int row = 16 * w + lg * 4 + r;
                *(unsigned short*)(L + OFF_P + row * 144 + (nt2 * 16 + lr) * 2) = f2bf(pw[nt2][r]);
            }
        // PV: O (16x32) = P (16x64) @ V (64x32)
        f32x4 o0 = {0.f,0.f,0.f,0.f}, o1 = o0;
        #pragma unroll
        for (int ks2 = 0; ks2 < 2; ++ks2) {
            bf16x8 ap  = *(const bf16x8*)(L + OFF_P + (16 * w + lr) * 144 + (ks2 * 32 + lg * 8) * 2);
            bf16x8 bv0 = *(const bf16x8*)(L + OFF_VT + (unsigned)(h * DH + lr) * 144 + (ks2 * 32 + lg * 8) * 2);
            bf16x8 bv1 = *(const bf16x8*)(L + OFF_VT + (unsigned)(h * DH + 16 + lr) * 144 + (ks2 * 32 + lg * 8) * 2);
            o0 = __builtin_amdgcn_mfma_f32_16x16x32_bf16(ap, bv0, o0, 0, 0, 0);
            o1 = __builtin_amdgcn_mfma_f32_16x16x32_bf16(ap, bv1, o1, 0, 0, 0);
        }
        unsigned short* ob = att + ((size_t)seq * NTOK) * DI + h * DH;
        #pragma unroll
        for (int r = 0; r < 4; ++r) {
            int tok = 16 * w + lg * 4 + r;
            if (tok < NTOK) {
                float g = *(const float*)(L + OFF_G + (h * 64 + tok) * 4);
                ob[(size_t)tok * DI + lr]      = f2bf(o0[r] * g);
                ob[(size_t)tok * DI + 16 + lr] = f2bf(o1[r] * g);
            }
        }
    }
}

// out(100352x512) = att(100352x256 bf16) @ w_out; 64-row blocks, wave = 16-row M-tile
__global__ __launch_bounds__(256) void k_out(const unsigned short* __restrict__ att,
                                             const unsigned short* __restrict__ wopk,
                                             float* __restrict__ out) {
    int t = threadIdx.x, w = t >> 6, l = t & 63, lr = l & 15, lg = l >> 4;
    size_t m0 = (size_t)blockIdx.x * 64 + w * 16;
    const bf16x8* wb = (const bf16x8*)wopk;
    f32x4 acc[32];
    #pragma unroll
    for (int nt = 0; nt < 32; ++nt) acc[nt] = f32x4{0.f, 0.f, 0.f, 0.f};
    #pragma unroll 2
    for (int ks = 0; ks < 8; ++ks) {
        bf16x8 a = *(const bf16x8*)(att + (m0 + lr) * DI + ks * 32 + lg * 8);
        #pragma unroll
        for (int nt = 0; nt < 32; ++nt) {
            bf16x8 b = wb[(nt * 8 + ks) * 64 + l];
            acc[nt] = __builtin_amdgcn_mfma_f32_16x16x32_bf16(a, b, acc[nt], 0, 0, 0);
        }
    }
    #pragma unroll
    for (int nt = 0; nt < 32; ++nt)
        #pragma unroll
        for (int r = 0; r < 4; ++r)
            out[(m0 + lg * 4 + r) * DIMD + nt * 16 + lr] = acc[nt][r];
}

extern "C" void kernel_launch(void* const* d_in, const int* in_sizes, int n_in,
                              void* d_out, int out_size, void* d_ws, size_t ws_size,
                              hipStream_t stream) {
    const float* x     = (const float*)d_in[0];
    const float* rote  = (const float*)d_in[1];
    const float* gamma = (const float*)d_in[2];
    const float* wqkv  = (const float*)d_in[3];
    const float* wg    = (const float*)d_in[4];
    const float* bg    = (const float*)d_in[5];
    const float* wout  = (const float*)d_in[6];
    float* ws = (float*)d_ws;
    unsigned short* wpk  = (unsigned short*)(ws + WS_WPK);
    unsigned short* wopk = (unsigned short*)(ws + WS_WOPK);
    unsigned short* att  = (unsigned short*)(ws + WS_ATT);
    unsigned short* xnp  = (unsigned short*)d_out;   // xn bf16 scratch in d_out (consumed before k_out overwrites)

    k_rope<<<7, 256, 0, stream>>>(rote, ws);
    k_pack<<<1568, 256, 0, stream>>>(wqkv, wg, wpk);
    k_pack_out<<<512, 256, 0, stream>>>(wout, wopk);
    k_norm<<<25088, 256, 0, stream>>>(x, gamma, xnp);
    k_attn<<<2048, 256, 0, stream>>>(xnp, ws, wpk, bg, att);
    k_out<<<1568, 256, 0, stream>>>(att, wopk, (float*)d_out);
}